// Round 5
// baseline (19.767 us; speedup 1.0000x reference)
//
#include <hip/hip_runtime.h>

// out[b,i,j,c] = sum_d tanh(start[b,c,i,d] + end[b,c,j,d]) * v[d]
// B=2, C=8, L=256, D=128.
//
// tanh(x) = 1 - 2/(e^{2x}+1);  e^{2(s+e)} = Es*Ee, Es=exp2(K*s), K=2*log2(e).
// Per d-quad all 4 divisions merge into ONE rcp:
//   sum_d v_d/q_d = (n01*cd + n23*ab)/(ab*cd),  q_d = fma(Es,Ee,1)
// -> 14 full-rate VALU + 1 trans per 4 elements.  out = sum(v) - 2*sum.
//
// R4 lesson: kernel ran at LDS-pipe + VALU-pipe SUM; LDS (4 B/elem) was the
// bigger pipe. Fix: 4x4 register blocking (2 B/elem, half the ds_read count)
// WITHOUT losing occupancy, by splitting d across the block's 4 waves:
// wave g covers d in [32g, 32g+32) for the whole 32x32 tile. 1024 blocks,
// 4 blocks/CU, 4 waves/SIMD. Skewed LDS tree combines the 4 partials.

#define LDIM 256
#define DDIM 128
#define DPAD 132   // rows stride 132 words: strided-row b128 reads hit all banks once

__global__ __launch_bounds__(256, 4) void span_tanh_dot_kernel(
    const float* __restrict__ start_h,
    const float* __restrict__ end_h,
    const float* __restrict__ v,
    float* __restrict__ out,
    int C)
{
    __shared__ float s_t[32][DPAD];
    __shared__ float e_t[32][DPAD];
    __shared__ float s_vsum;

    const int bc = blockIdx.z;            // b*C + c
    const int i0 = blockIdx.y * 32;
    const int j0 = blockIdx.x * 32;
    const int tx = threadIdx.x;           // 0..7
    const int ty = threadIdx.y;           // 0..7
    const int g  = threadIdx.z;           // 0..3: wave = d-group
    const int t  = ty * 8 + tx;           // lane within wave
    const int tid = g * 64 + t;

    const float K = 2.8853900817779268f;  // 2*log2(e)

    const float* sg = start_h + ((size_t)bc * LDIM + i0) * DDIM;
    const float* eg = end_h   + ((size_t)bc * LDIM + j0) * DDIM;

    // stage 32x128 tiles of Es=exp2(K*s), Ee=exp2(K*e); 4 float4/thread/tensor
    #pragma unroll
    for (int k = 0; k < 4; ++k) {
        const int idx = tid + k * 256;
        const int r  = idx >> 5;
        const int c4 = (idx & 31) << 2;
        float4 a = *(const float4*)(sg + r * DDIM + c4);
        a.x = __builtin_amdgcn_exp2f(K * a.x);
        a.y = __builtin_amdgcn_exp2f(K * a.y);
        a.z = __builtin_amdgcn_exp2f(K * a.z);
        a.w = __builtin_amdgcn_exp2f(K * a.w);
        *(float4*)(&s_t[r][c4]) = a;
        float4 b = *(const float4*)(eg + r * DDIM + c4);
        b.x = __builtin_amdgcn_exp2f(K * b.x);
        b.y = __builtin_amdgcn_exp2f(K * b.y);
        b.z = __builtin_amdgcn_exp2f(K * b.z);
        b.w = __builtin_amdgcn_exp2f(K * b.w);
        *(float4*)(&e_t[r][c4]) = b;
    }

    // sum(v): wave 0 butterfly, broadcast via LDS
    if (g == 0) {
        float2 vv = *(const float2*)(v + 2 * t);
        float p = vv.x + vv.y;
        #pragma unroll
        for (int off = 1; off < 64; off <<= 1) p += __shfl_xor(p, off);
        if (t == 0) s_vsum = p;
    }
    __syncthreads();

    float acc[4][4];
    #pragma unroll
    for (int a = 0; a < 4; ++a)
        #pragma unroll
        for (int b = 0; b < 4; ++b) acc[a][b] = 0.0f;

    const int dbase = g * 32;

    #pragma unroll 2
    for (int it = 0; it < 8; ++it) {
        const int d = dbase + it * 4;
        float4 S[4], E[4];
        #pragma unroll
        for (int k = 0; k < 4; ++k) {
            S[k] = *(const float4*)(&s_t[ty + 8 * k][d]);  // 8 addrs, all banks once
            E[k] = *(const float4*)(&e_t[tx + 8 * k][d]);  // 8 addrs, all banks once
        }
        const float4 vv = *(const float4*)(v + d);

        #pragma unroll
        for (int a = 0; a < 4; ++a) {
            #pragma unroll
            for (int b = 0; b < 4; ++b) {
                float q0 = fmaf(S[a].x, E[b].x, 1.0f);
                float q1 = fmaf(S[a].y, E[b].y, 1.0f);
                float q2 = fmaf(S[a].z, E[b].z, 1.0f);
                float q3 = fmaf(S[a].w, E[b].w, 1.0f);
                float ab = q0 * q1, cd = q2 * q3;
                float n01 = fmaf(vv.x, q1, vv.y * q0);
                float n23 = fmaf(vv.z, q3, vv.w * q2);
                float N = fmaf(n01, cd, n23 * ab);
                float r = __builtin_amdgcn_rcpf(ab * cd);
                acc[a][b] = fmaf(N, r, acc[a][b]);
            }
        }
    }

    // combine 4 d-partials via LDS tree (alias dead s_t; 16 KB <= 16.9 KB).
    // Skew index by +t so stride-16-word accesses spread across banks.
    __syncthreads();                       // all reads of s_t/e_t done
    float4* redv = (float4*)(&s_t[0][0]);
    #pragma unroll
    for (int a = 0; a < 4; ++a) {
        float4 row; row.x = acc[a][0]; row.y = acc[a][1];
        row.z = acc[a][2]; row.w = acc[a][3];
        redv[(g * 64 + t) * 4 + ((a + t) & 3)] = row;
    }
    __syncthreads();

    float4 sum = redv[t * 4 + ((g + t) & 3)];                 // src 0
    #pragma unroll
    for (int src = 1; src < 4; ++src) {
        float4 r4 = redv[(src * 64 + t) * 4 + ((g + t) & 3)];
        sum.x += r4.x; sum.y += r4.y; sum.z += r4.z; sum.w += r4.w;
    }

    // wave g writes output rows i = i0 + ty + 8g, cols {tx, tx+8, tx+16, tx+24}
    const int b_ = bc / C;
    const int c_ = bc - b_ * C;
    const float Sv = s_vsum;
    const int i = i0 + ty + 8 * g;
    const size_t rowbase = (((size_t)b_ * LDIM + i) * LDIM) * C + c_;
    out[rowbase + (size_t)(j0 + tx     ) * C] = fmaf(-2.f, sum.x, Sv);
    out[rowbase + (size_t)(j0 + tx +  8) * C] = fmaf(-2.f, sum.y, Sv);
    out[rowbase + (size_t)(j0 + tx + 16) * C] = fmaf(-2.f, sum.z, Sv);
    out[rowbase + (size_t)(j0 + tx + 24) * C] = fmaf(-2.f, sum.w, Sv);
}

extern "C" void kernel_launch(void* const* d_in, const int* in_sizes, int n_in,
                              void* d_out, int out_size, void* d_ws, size_t ws_size,
                              hipStream_t stream) {
    const float* start_h = (const float*)d_in[0];
    const float* end_h   = (const float*)d_in[1];
    const float* v       = (const float*)d_in[2];
    float* out = (float*)d_out;

    const int BC = in_sizes[0] / (LDIM * DDIM);  // B*C = 16
    const int C  = 8;

    dim3 grid(LDIM / 32, LDIM / 32, BC);   // (8, 8, 16) = 1024 blocks, 4/CU
    dim3 block(8, 8, 4);                   // 256 threads; wave g = d-group g
    span_tanh_dot_kernel<<<grid, block, 0, stream>>>(start_h, end_h, v, out, C);
}

// Round 6
// 19.549 us; speedup vs baseline: 1.0111x; 1.0111x over previous
//
#include <hip/hip_runtime.h>

// out[b,i,j,c] = sum_d tanh(start[b,c,i,d] + end[b,c,j,d]) * v[d]
// B=2, C=8, L=256, D=128.
//
// tanh(x) = 1 - 2/(e^{2x}+1);  e^{2(s+e)} = Es*Ee, Es=exp2(K*s), K=2*log2(e).
// Per d-quad all 4 divisions merge into ONE rcp (14 full-rate + 1 trans / 4 elem).
// out = sum(v) - 2 * sum_d v_d/q_d.
//
// R5 lesson: NOT throughput-bound (halving LDS instrs changed nothing; cutting
// VALU 28% gave 7%). Latency-bound: every round so far had exactly 16 QUAD
// chains in flight per SIMD (~40 cyc serial chain each, rcp-dominated) -> ~60%
// issue-idle. Fix: 8 waves/SIMD (100% occupancy) x 4 chains/thread = 32 chains.
// 512-thr blocks: wave = (tile-quarter q) x (d-half h); 2x2 blocking; VGPR<=64
// via __launch_bounds__(512,8); v through readfirstlane -> s_load (no VGPRs).

#define LDIM 256
#define DDIM 128
#define DPAD 132   // (4*row + d) mod 32 covers all banks once per 8-row read set

__global__ __launch_bounds__(512, 8) void span_tanh_dot_kernel(
    const float* __restrict__ start_h,
    const float* __restrict__ end_h,
    const float* __restrict__ v,
    float* __restrict__ out,
    int C)
{
    __shared__ float s_t[32][DPAD];      // 16.9 KB
    __shared__ float e_t[32][DPAD];      // 16.9 KB
    __shared__ float4 red[4 * 64];       // 4 KB: h=1 partials per quarter
    __shared__ float s_vsum;

    const int bc = blockIdx.z;           // b*C + c
    const int i0 = blockIdx.y * 32;
    const int j0 = blockIdx.x * 32;
    const int tx = threadIdx.x;          // 0..7
    const int ty = threadIdx.y;          // 0..7
    const int g  = threadIdx.z;          // 0..7 = wave id (64 consecutive tids)
    const int t  = ty * 8 + tx;          // lane in wave
    const int tid = g * 64 + t;

    const int q  = g & 3;                // tile quarter (16x16)
    const int h  = g >> 2;               // d half: [0,64) or [64,128)
    const int qi = q >> 1, qj = q & 1;

    const float K = 2.8853900817779268f; // 2*log2(e)

    const float* sg = start_h + ((size_t)bc * LDIM + i0) * DDIM;
    const float* eg = end_h   + ((size_t)bc * LDIM + j0) * DDIM;

    // stage 32x128 tiles of Es=exp2(K*s), Ee=exp2(K*e); 2 float4/thread/tensor
    #pragma unroll
    for (int k = 0; k < 2; ++k) {
        const int idx = tid + k * 512;
        const int r  = idx >> 5;
        const int c4 = (idx & 31) << 2;
        float4 a = *(const float4*)(sg + r * DDIM + c4);
        a.x = __builtin_amdgcn_exp2f(K * a.x);
        a.y = __builtin_amdgcn_exp2f(K * a.y);
        a.z = __builtin_amdgcn_exp2f(K * a.z);
        a.w = __builtin_amdgcn_exp2f(K * a.w);
        *(float4*)(&s_t[r][c4]) = a;
        float4 b = *(const float4*)(eg + r * DDIM + c4);
        b.x = __builtin_amdgcn_exp2f(K * b.x);
        b.y = __builtin_amdgcn_exp2f(K * b.y);
        b.z = __builtin_amdgcn_exp2f(K * b.z);
        b.w = __builtin_amdgcn_exp2f(K * b.w);
        *(float4*)(&e_t[r][c4]) = b;
    }

    // sum(v): wave 0 butterfly
    if (g == 0) {
        float2 vv = *(const float2*)(v + 2 * t);
        float p = vv.x + vv.y;
        #pragma unroll
        for (int off = 1; off < 64; off <<= 1) p += __shfl_xor(p, off);
        if (t == 0) s_vsum = p;
    }
    __syncthreads();

    const int r0 = qi * 16 + ty;         // rows r0, r0+8 of the tile
    const int c0 = qj * 16 + tx;         // cols c0, c0+8
    // wave-uniform d base so v-loads become s_load (SGPR, no VGPR cost)
    const int dbase = __builtin_amdgcn_readfirstlane(h * 64);

    float acc00 = 0.f, acc01 = 0.f, acc10 = 0.f, acc11 = 0.f;

#define QUAD(ACC, S, E)                                            \
    {                                                              \
        float q0 = fmaf((S).x, (E).x, 1.0f);                       \
        float q1 = fmaf((S).y, (E).y, 1.0f);                       \
        float q2 = fmaf((S).z, (E).z, 1.0f);                       \
        float q3 = fmaf((S).w, (E).w, 1.0f);                       \
        float ab = q0 * q1, cd = q2 * q3;                          \
        float n01 = fmaf(v0, q1, v1 * q0);                         \
        float n23 = fmaf(v2, q3, v3 * q2);                         \
        float N = fmaf(n01, cd, n23 * ab);                         \
        float r = __builtin_amdgcn_rcpf(ab * cd);                  \
        ACC = fmaf(N, r, ACC);                                     \
    }

    #pragma unroll 2
    for (int it = 0; it < 16; ++it) {
        const int d = dbase + it * 4;
        const float4 sa = *(const float4*)(&s_t[r0    ][d]);  // 8 addr, all banks
        const float4 sb = *(const float4*)(&s_t[r0 + 8][d]);
        const float4 ea = *(const float4*)(&e_t[c0    ][d]);
        const float4 eb = *(const float4*)(&e_t[c0 + 8][d]);
        const float v0 = v[d], v1 = v[d + 1], v2 = v[d + 2], v3 = v[d + 3];

        QUAD(acc00, sa, ea);
        QUAD(acc01, sa, eb);
        QUAD(acc10, sb, ea);
        QUAD(acc11, sb, eb);
    }
#undef QUAD

    // combine d-halves: h=1 parks partials in LDS, h=0 adds and stores.
    if (h == 1) red[q * 64 + t] = make_float4(acc00, acc01, acc10, acc11);
    __syncthreads();
    if (h == 0) {
        const float4 p = red[q * 64 + t];
        acc00 += p.x; acc01 += p.y; acc10 += p.z; acc11 += p.w;

        const int b_ = bc / C;
        const int c_ = bc - b_ * C;
        const float Sv = s_vsum;
        const int ia = i0 + r0, ib = ia + 8;
        const int ja = j0 + c0, jb = ja + 8;
        const size_t basea = (((size_t)b_ * LDIM + ia) * LDIM) * C + c_;
        const size_t baseb = (((size_t)b_ * LDIM + ib) * LDIM) * C + c_;
        out[basea + (size_t)ja * C] = fmaf(-2.f, acc00, Sv);
        out[basea + (size_t)jb * C] = fmaf(-2.f, acc01, Sv);
        out[baseb + (size_t)ja * C] = fmaf(-2.f, acc10, Sv);
        out[baseb + (size_t)jb * C] = fmaf(-2.f, acc11, Sv);
    }
}

extern "C" void kernel_launch(void* const* d_in, const int* in_sizes, int n_in,
                              void* d_out, int out_size, void* d_ws, size_t ws_size,
                              hipStream_t stream) {
    const float* start_h = (const float*)d_in[0];
    const float* end_h   = (const float*)d_in[1];
    const float* v       = (const float*)d_in[2];
    float* out = (float*)d_out;

    const int BC = in_sizes[0] / (LDIM * DDIM);  // B*C = 16
    const int C  = 8;

    dim3 grid(LDIM / 32, LDIM / 32, BC);   // (8, 8, 16) = 1024 blocks
    dim3 block(8, 8, 8);                   // 512 threads = 8 waves
    span_tanh_dot_kernel<<<grid, block, 0, stream>>>(start_h, end_h, v, out, C);
}